// Round 5
// baseline (280.465 us; speedup 1.0000x reference)
//
#include <hip/hip_runtime.h>
#include <stdint.h>

#define NCLS 36
#define HDIM 256
#define BSZ  32
#define LLOC 196
#define DIN  1024
#define NCH  9216          // NCLS*HDIM
#define NCH4 2304          // NCH/4
#define XG_N 294912        // BSZ*NCH
#define SC_N 225792        // BSZ*NCLS*LLOC
#define SC_N4 56448        // SC_N/4
#define V_N  1179648       // BSZ*NCLS*DIN

__device__ __forceinline__ void fma4(float4& a, float s, const float4& b) {
  a.x += s * b.x; a.y += s * b.y; a.z += s * b.z; a.w += s * b.w;
}
__device__ __forceinline__ float dot4(const float4& a, const float4& b) {
  return a.x * b.x + a.y * b.y + a.z * b.z + a.w * b.w;
}

// ---------------------------------------------------------------------------
// kA: XGP[ks][b][n] = sum_{k in ks*64..+64} gap[b][k]*Wg[k][n]
// grid (36 nt256, 16 ks64), 256 thr. Wave w owns 16 k-rows; lane owns 1 f4 of
// n -> every Wg load = 1 KB contiguous, zero redundancy. 3-phase LDS reduce.
__global__ __launch_bounds__(256) void kA_xg(
    const float* __restrict__ Wg, const float* __restrict__ gap,
    float* __restrict__ XGP) {
  __shared__ __align__(16) float4 gs[512];          // [32 b][16 k4] = 8 KB
  __shared__ __align__(16) float4 red[4096];        // [2][32 b][64 lane] = 64 KB
  const int tid = threadIdx.x;
  const int nt = blockIdx.x, ks = blockIdx.y;
  const int n0 = nt * 256, k0 = ks * 64;
  const float4* gap4 = (const float4*)gap;
  for (int i = tid; i < 512; i += 256)
    gs[i] = gap4[(size_t)(i >> 4) * 256 + ks * 16 + (i & 15)];
  __syncthreads();
  const int w = tid >> 6, lane = tid & 63;
  float4 acc[32] = {};
  const float* wp = Wg + (size_t)(k0 + w * 16) * NCH + n0 + lane * 4;
  for (int kq = 0; kq < 4; ++kq) {
    float4 wr[4];
    #pragma unroll
    for (int kk = 0; kk < 4; ++kk)
      wr[kk] = *(const float4*)(wp + (size_t)(kq * 4 + kk) * NCH);
    const int k4g = w * 4 + kq;
    #pragma unroll
    for (int b = 0; b < 32; ++b) {
      float4 g = gs[b * 16 + k4g];                  // wave-wide broadcast
      fma4(acc[b], g.x, wr[0]); fma4(acc[b], g.y, wr[1]);
      fma4(acc[b], g.z, wr[2]); fma4(acc[b], g.w, wr[3]);
    }
  }
  __syncthreads();
  if (w >= 2) {
    #pragma unroll
    for (int b = 0; b < 32; ++b) red[(w - 2) * 2048 + b * 64 + lane] = acc[b];
  }
  __syncthreads();
  if (w < 2) {
    #pragma unroll
    for (int b = 0; b < 32; ++b) {
      float4 t = red[w * 2048 + b * 64 + lane];
      acc[b].x += t.x; acc[b].y += t.y; acc[b].z += t.z; acc[b].w += t.w;
    }
    #pragma unroll
    for (int b = 0; b < 32; ++b) red[w * 2048 + b * 64 + lane] = acc[b];
  }
  __syncthreads();
  #pragma unroll
  for (int i = 0; i < 8; ++i) {
    int b = w * 8 + i;
    float4 a = red[b * 64 + lane];
    float4 c = red[2048 + b * 64 + lane];
    a.x += c.x; a.y += c.y; a.z += c.z; a.w += c.w;
    *(float4*)&XGP[(size_t)ks * XG_N + (size_t)b * NCH + n0 + lane * 4] = a;
  }
}

// ---------------------------------------------------------------------------
// kB: XG = bg + sum_{p<16} XGP[p].  grid 288 x 256 (1 f4/thread).
__global__ __launch_bounds__(256) void kB_red(
    const float* __restrict__ XGP, const float* __restrict__ bg,
    float* __restrict__ XG) {
  const int b = blockIdx.x / 9;
  const int j = (blockIdx.x % 9) * 256 + threadIdx.x;   // 0..2303
  const size_t off = (size_t)b * NCH4 + j;
  const float4* p4 = (const float4*)XGP;
  float4 s = ((const float4*)bg)[j];
  #pragma unroll
  for (int p = 0; p < 16; ++p) {
    float4 t = p4[(size_t)p * (XG_N / 4) + off];
    s.x += t.x; s.y += t.y; s.z += t.z; s.w += t.w;
  }
  ((float4*)XG)[off] = s;
}

// ---------------------------------------------------------------------------
// kC: V[b][c][k] = sum_h XG[b][c,h] * Wl[k][c*256+h]
// grid (36 c, 16 kt64), 256 thr, 96 KB LDS. Wl k-tile staged with COALESCED
// 1 KB row loads (rotation swizzle); xg staged with bslot swizzle.
// Thread tile 4 k x 8 b; 4 waves split h (16 h4 each); 3-phase LDS reduce.
// Per h4: 12 conflict-free LDS b128 reads -> 32 dot4 (VALU-bound).
__global__ __launch_bounds__(256) void kC_V(
    const float* __restrict__ Wl, const float* __restrict__ XG,
    float* __restrict__ V) {
  __shared__ __align__(16) float4 wl_s[4096];       // [64 k][64 h4] rot = 64 KB
  __shared__ __align__(16) float4 xg_s[2048];       // [32 b][64 h4] swz = 32 KB
  const int tid = threadIdx.x;
  const int c = blockIdx.x, kt = blockIdx.y;
  const int k0 = kt * 64;
  // stage Wl tile: rows contiguous (1 KB per 64-lane group), rotated cols
  for (int i = tid; i < 4096; i += 256) {
    int r = i >> 6, g = i & 63;
    wl_s[r * 64 + ((g + r) & 63)] =
        *(const float4*)&Wl[(size_t)(k0 + r) * NCH + c * 256 + g * 4];
  }
  // stage xg: [32 b][64 h4], col swizzled by b>>3 (kills stride-8-b conflicts)
  const float4* xg4 = (const float4*)XG;
  for (int i = tid; i < 2048; i += 256) {
    int b = i >> 6, h4 = i & 63;
    xg_s[b * 64 + ((h4 + (b >> 3)) & 63)] = xg4[(size_t)b * NCH4 + c * 64 + h4];
  }
  __syncthreads();
  const int w = tid >> 6, lane = tid & 63;
  const int k16 = lane & 15;                        // k = k16 + 16*kk
  const int bslot = lane >> 4;                      // b0 = bslot*8
  const int b0 = bslot * 8;
  float acc[4][8] = {};
  for (int h4 = w * 16; h4 < w * 16 + 16; ++h4) {
    float4 wv[4];
    #pragma unroll
    for (int kk = 0; kk < 4; ++kk) {
      int k = k16 + 16 * kk;
      wv[kk] = wl_s[k * 64 + ((h4 + k) & 63)];      // 2-way max: free
    }
    const int xcol = (h4 + bslot) & 63;             // 4 distinct banks
    #pragma unroll
    for (int bb = 0; bb < 8; ++bb) {
      float4 x = xg_s[(b0 + bb) * 64 + xcol];
      #pragma unroll
      for (int kk = 0; kk < 4; ++kk) acc[kk][bb] += dot4(wv[kk], x);
    }
  }
  __syncthreads();                                  // wl_s reads done
  float* red = (float*)wl_s;                        // [2][32 b][64 k] = 16 KB
  if (w >= 2) {
    #pragma unroll
    for (int kk = 0; kk < 4; ++kk)
      #pragma unroll
      for (int bb = 0; bb < 8; ++bb)
        red[(w - 2) * 2048 + (b0 + bb) * 64 + k16 + 16 * kk] = acc[kk][bb];
  }
  __syncthreads();
  if (w < 2) {
    #pragma unroll
    for (int kk = 0; kk < 4; ++kk)
      #pragma unroll
      for (int bb = 0; bb < 8; ++bb) {
        int o = w * 2048 + (b0 + bb) * 64 + k16 + 16 * kk;
        red[o] += acc[kk][bb];
      }
  }
  __syncthreads();
  const float4* r04 = (const float4*)red;           // [512] f4
  float4* v4 = (float4*)V;
  for (int i = tid; i < 512; i += 256) {
    float4 a = r04[i], bv = r04[512 + i];
    a.x += bv.x; a.y += bv.y; a.z += bv.z; a.w += bv.w;
    int b = i >> 4, kq = i & 15;
    v4[(size_t)(b * NCLS + c) * 256 + kt * 16 + kq] = a;
  }
}

// ---------------------------------------------------------------------------
// kD: SCP[ks][b][c][l] = sum_{k in ks*64..+64} loc[b][l][k]*V[b][c][k]
// grid (32 b, 16 ks64) = 512 (2 blocks/CU at 58 KB), 256 thr.
// loc rows rotation-swizzled; thread tile: 4 l x 9 c.
__global__ __launch_bounds__(256) void kD_scores(
    const float* __restrict__ local_f, const float* __restrict__ V,
    float* __restrict__ SCP) {
  __shared__ __align__(16) float4 loc_s[3136];      // [196][16] rot = 49 KB
  __shared__ __align__(16) float4 v_s[576];         // [36][16] = 9 KB
  const int tid = threadIdx.x;
  const int b = blockIdx.x, ks = blockIdx.y;
  const float4* lf4 = (const float4*)local_f;
  for (int i = tid; i < 3136; i += 256) {
    int r = i >> 4, g = i & 15;
    loc_s[r * 16 + ((g + r) & 15)] = lf4[(size_t)(b * LLOC + r) * 256 + ks * 16 + g];
  }
  const float4* v4 = (const float4*)V;
  for (int i = tid; i < 576; i += 256) {
    int cc = i >> 4, g = i & 15;
    v_s[i] = v4[(size_t)(b * NCLS + cc) * 256 + ks * 16 + g];
  }
  __syncthreads();
  const int lg = tid & 63, cg = tid >> 6;
  float acc[4][9] = {};
  for (int k4 = 0; k4 < 16; ++k4) {
    float4 vv[9];
    #pragma unroll
    for (int ci = 0; ci < 9; ++ci) vv[ci] = v_s[(cg * 9 + ci) * 16 + k4];
    #pragma unroll
    for (int i = 0; i < 4; ++i) {
      int l = lg + 64 * i;
      if (l < LLOC) {
        float4 a = loc_s[l * 16 + ((k4 + l) & 15)];
        #pragma unroll
        for (int ci = 0; ci < 9; ++ci) acc[i][ci] += dot4(a, vv[ci]);
      }
    }
  }
  #pragma unroll
  for (int i = 0; i < 4; ++i) {
    int l = lg + 64 * i;
    if (l < LLOC) {
      #pragma unroll
      for (int ci = 0; ci < 9; ++ci)
        SCP[(size_t)ks * SC_N + (size_t)(b * NCLS + cg * 9 + ci) * LLOC + l] = acc[i][ci];
    }
  }
}

// ---------------------------------------------------------------------------
// kE: sum 16 partials (float4) + softmax over l. grid (32,36) x 64 (49 active).
__global__ __launch_bounds__(64) void kE_softmax(
    const float* __restrict__ SCP, float* __restrict__ ATT) {
  const int b = blockIdx.x, c = blockIdx.y, t = threadIdx.x;
  const size_t base4 = (size_t)(b * NCLS + c) * 49;
  const float4* s4 = (const float4*)SCP;
  float4 s = {0.f, 0.f, 0.f, 0.f};
  float m = -1e30f;
  if (t < 49) {
    s = s4[base4 + t];
    #pragma unroll
    for (int p = 1; p < 16; ++p) {
      float4 x = s4[(size_t)p * SC_N4 + base4 + t];
      s.x += x.x; s.y += x.y; s.z += x.z; s.w += x.w;
    }
    m = fmaxf(fmaxf(s.x, s.y), fmaxf(s.z, s.w));
  }
  #pragma unroll
  for (int off = 32; off >= 1; off >>= 1) m = fmaxf(m, __shfl_xor(m, off));
  float4 e = {0.f, 0.f, 0.f, 0.f};
  float sum = 0.f;
  if (t < 49) {
    e.x = __expf(s.x - m); e.y = __expf(s.y - m);
    e.z = __expf(s.z - m); e.w = __expf(s.w - m);
    sum = e.x + e.y + e.z + e.w;
  }
  #pragma unroll
  for (int off = 32; off >= 1; off >>= 1) sum += __shfl_xor(sum, off);
  float inv = 1.0f / sum;
  if (t < 49) {
    e.x *= inv; e.y *= inv; e.z *= inv; e.w *= inv;
    ((float4*)ATT)[base4 + t] = e;
  }
}

// ---------------------------------------------------------------------------
// kF: U[b][c][k] = sum_l att[b][c][l]*loc[b][l][k]
// grid (32 b, 8 ks128) = 256, 256 thr. loc streamed from GLOBAL (coalesced,
// L3-resident after kD); att (27.6 KB) + lh-reduce (72 KB) in LDS.
__global__ __launch_bounds__(256) void kF_U(
    const float* __restrict__ local_f, const float* __restrict__ ATT,
    float* __restrict__ U) {
  __shared__ __align__(16) float4 att_s[1764];      // [36][49] = 27.6 KB
  __shared__ __align__(16) float4 red[4608];        // [4][36][32] = 72 KB
  const int tid = threadIdx.x;
  const int b = blockIdx.x, ks = blockIdx.y;
  const int k0 = ks * 128;
  const float4* at4 = (const float4*)ATT;
  for (int i = tid; i < 1764; i += 256) {
    int cc = i / 49, l4 = i - cc * 49;
    att_s[i] = at4[(size_t)(b * NCLS + cc) * 49 + l4];
  }
  __syncthreads();
  const int kg = tid & 15, cg = (tid >> 4) & 3, lh = tid >> 6;
  float4 acc[9][2] = {};
  const float* lbase = local_f + (size_t)b * LLOC * DIN + k0 + kg * 8;
  for (int l4 = lh; l4 < 49; l4 += 4) {
    float4 lv[4][2];
    #pragma unroll
    for (int ll = 0; ll < 4; ++ll) {
      const float* p = lbase + (size_t)(l4 * 4 + ll) * DIN;
      lv[ll][0] = *(const float4*)p;
      lv[ll][1] = *(const float4*)(p + 4);
    }
    #pragma unroll
    for (int ci = 0; ci < 9; ++ci) {
      float4 av = att_s[(cg * 9 + ci) * 49 + l4];
      fma4(acc[ci][0], av.x, lv[0][0]); fma4(acc[ci][1], av.x, lv[0][1]);
      fma4(acc[ci][0], av.y, lv[1][0]); fma4(acc[ci][1], av.y, lv[1][1]);
      fma4(acc[ci][0], av.z, lv[2][0]); fma4(acc[ci][1], av.z, lv[2][1]);
      fma4(acc[ci][0], av.w, lv[3][0]); fma4(acc[ci][1], av.w, lv[3][1]);
    }
  }
  #pragma unroll
  for (int ci = 0; ci < 9; ++ci) {
    int c = cg * 9 + ci;
    red[lh * 1152 + c * 32 + kg * 2 + 0] = acc[ci][0];
    red[lh * 1152 + c * 32 + kg * 2 + 1] = acc[ci][1];
  }
  __syncthreads();
  float4* u4 = (float4*)U;
  for (int i = tid; i < 1152; i += 256) {
    float4 s = red[i];
    #pragma unroll
    for (int p = 1; p < 4; ++p) {
      float4 t = red[p * 1152 + i];
      s.x += t.x; s.y += t.y; s.z += t.z; s.w += t.w;
    }
    u4[(size_t)(b * NCLS + (i >> 5)) * 256 + ks * 32 + (i & 31)] = s;
  }
}

// ---------------------------------------------------------------------------
// kG: WSP[ks][b][c*256+h] = sum_{k in ks*64..+64} U[b][c][k]*Wl[k][c*256+h]
// Exact mirror of kA. Wl read ONCE, 1 KB/instr coalesced, zero redundancy.
__global__ __launch_bounds__(256) void kG_ws(
    const float* __restrict__ Wl, const float* __restrict__ U,
    float* __restrict__ WSP) {
  __shared__ __align__(16) float4 us[512];          // [32 b][16 k4] = 8 KB
  __shared__ __align__(16) float4 red[4096];        // [2][32 b][64 lane] = 64 KB
  const int tid = threadIdx.x;
  const int c = blockIdx.x, ks = blockIdx.y;
  const int k0 = ks * 64;
  const float4* u4 = (const float4*)U;
  for (int i = tid; i < 512; i += 256)
    us[i] = u4[(size_t)((i >> 4) * NCLS + c) * 256 + ks * 16 + (i & 15)];
  __syncthreads();
  const int w = tid >> 6, lane = tid & 63;
  float4 acc[32] = {};
  const float* wp = Wl + (size_t)(k0 + w * 16) * NCH + c * HDIM + lane * 4;
  for (int kq = 0; kq < 4; ++kq) {
    float4 wr[4];
    #pragma unroll
    for (int kk = 0; kk < 4; ++kk)
      wr[kk] = *(const float4*)(wp + (size_t)(kq * 4 + kk) * NCH);
    const int k4g = w * 4 + kq;
    #pragma unroll
    for (int b = 0; b < 32; ++b) {
      float4 g = us[b * 16 + k4g];                  // wave-wide broadcast
      fma4(acc[b], g.x, wr[0]); fma4(acc[b], g.y, wr[1]);
      fma4(acc[b], g.z, wr[2]); fma4(acc[b], g.w, wr[3]);
    }
  }
  __syncthreads();
  if (w >= 2) {
    #pragma unroll
    for (int b = 0; b < 32; ++b) red[(w - 2) * 2048 + b * 64 + lane] = acc[b];
  }
  __syncthreads();
  if (w < 2) {
    #pragma unroll
    for (int b = 0; b < 32; ++b) {
      float4 t = red[w * 2048 + b * 64 + lane];
      acc[b].x += t.x; acc[b].y += t.y; acc[b].z += t.z; acc[b].w += t.w;
    }
    #pragma unroll
    for (int b = 0; b < 32; ++b) red[w * 2048 + b * 64 + lane] = acc[b];
  }
  __syncthreads();
  #pragma unroll
  for (int i = 0; i < 8; ++i) {
    int b = w * 8 + i;
    float4 a = red[b * 64 + lane];
    float4 cc = red[2048 + b * 64 + lane];
    a.x += cc.x; a.y += cc.y; a.z += cc.z; a.w += cc.w;
    *(float4*)&WSP[(size_t)ks * XG_N + (size_t)b * NCH + c * HDIM + lane * 4] = a;
  }
}

// ---------------------------------------------------------------------------
// kH: ws = bl + sum16 WSP; hid = relu(ws@Wh+bh); heads. grid (32,12) x 256.
__global__ __launch_bounds__(256) void kH_heads(
    const float* __restrict__ Wh, const float* __restrict__ bh,
    const float* __restrict__ Wr, const float* __restrict__ br,
    const float* __restrict__ Wc, const float* __restrict__ bc,
    const float* __restrict__ bl,
    const float* __restrict__ WSP, float* __restrict__ out) {
  __shared__ float ws_s[3][HDIM];
  __shared__ float hid_s[3][HDIM];
  const int b = blockIdx.x, c0 = blockIdx.y * 3;
  const int j = threadIdx.x;
  #pragma unroll
  for (int ci = 0; ci < 3; ++ci) {
    size_t base = (size_t)b * NCH + (c0 + ci) * HDIM + j;
    float s = bl[(c0 + ci) * HDIM + j];
    #pragma unroll
    for (int p = 0; p < 16; ++p) s += WSP[(size_t)p * XG_N + base];
    ws_s[ci][j] = s;
  }
  __syncthreads();
  float acc[3] = {0, 0, 0};
  for (int h = 0; h < HDIM; ++h) {
    float whj = Wh[(size_t)h * HDIM + j];
    acc[0] += ws_s[0][h] * whj;
    acc[1] += ws_s[1][h] * whj;
    acc[2] += ws_s[2][h] * whj;
  }
  float bj = bh[j];
  #pragma unroll
  for (int ci = 0; ci < 3; ++ci) hid_s[ci][j] = fmaxf(acc[ci] + bj, 0.0f);
  __syncthreads();
  const int r = j >> 6, j0 = j & 63;
  for (int ci = 0; ci < 3; ++ci) {
    const int c = c0 + ci;
    float s = 0.f;
    #pragma unroll
    for (int m = 0; m < 4; ++m)
      s += hid_s[ci][j0 + 64 * m] * Wr[(j0 + 64 * m) * 4 + r];
    #pragma unroll
    for (int off = 32; off >= 1; off >>= 1) s += __shfl_xor(s, off);
    if (j0 == 0) out[(size_t)b * (NCLS * 4) + c * 4 + r] = s + br[r];
    if (r == 0) {
      float p = 0.f;
      #pragma unroll
      for (int m = 0; m < 4; ++m)
        p += hid_s[ci][j0 + 64 * m] * Wc[j0 + 64 * m];
      #pragma unroll
      for (int off = 32; off >= 1; off >>= 1) p += __shfl_xor(p, off);
      if (j0 == 0) out[BSZ * NCLS * 4 + b * NCLS + c] = p + bc[0];
    }
  }
}

// ---------------------------------------------------------------------------
extern "C" void kernel_launch(void* const* d_in, const int* in_sizes, int n_in,
                              void* d_out, int out_size, void* d_ws, size_t ws_size,
                              hipStream_t stream) {
  const float* local = (const float*)d_in[0];
  const float* gap   = (const float*)d_in[1];
  const float* Wl    = (const float*)d_in[2];
  const float* bl    = (const float*)d_in[3];
  const float* Wg    = (const float*)d_in[4];
  const float* bg    = (const float*)d_in[5];
  const float* Wh    = (const float*)d_in[6];
  const float* bh    = (const float*)d_in[7];
  const float* Wr    = (const float*)d_in[8];
  const float* br    = (const float*)d_in[9];
  const float* Wc    = (const float*)d_in[10];
  const float* bc    = (const float*)d_in[11];
  float* out         = (float*)d_out;

  // ws: XGP 16x1.2MB | XG 1.2 | V 4.7 | SCP 16x0.9 | ATT 0.9 | U 4.7 | WSP 16x1.2
  float* XGP = (float*)d_ws;
  float* XG  = XGP + (size_t)16 * XG_N;
  float* V   = XG + XG_N;
  float* SCP = V + V_N;
  float* ATT = SCP + (size_t)16 * SC_N;
  float* U   = ATT + SC_N;
  float* WSP = U + V_N;

  kA_xg     <<<dim3(36, 16), dim3(256), 0, stream>>>(Wg, gap, XGP);
  kB_red    <<<dim3(288),    dim3(256), 0, stream>>>(XGP, bg, XG);
  kC_V      <<<dim3(36, 16), dim3(256), 0, stream>>>(Wl, XG, V);
  kD_scores <<<dim3(32, 16), dim3(256), 0, stream>>>(local, V, SCP);
  kE_softmax<<<dim3(32, 36), dim3(64),  0, stream>>>(SCP, ATT);
  kF_U      <<<dim3(32, 8),  dim3(256), 0, stream>>>(local, ATT, U);
  kG_ws     <<<dim3(36, 16), dim3(256), 0, stream>>>(Wl, U, WSP);
  kH_heads  <<<dim3(32, 12), dim3(256), 0, stream>>>(Wh, bh, Wr, br, Wc, bc, bl, WSP, out);
}

// Round 6
// 258.328 us; speedup vs baseline: 1.0857x; 1.0857x over previous
//
#include <hip/hip_runtime.h>
#include <stdint.h>

#define NCLS 36
#define HDIM 256
#define BSZ  32
#define LLOC 196
#define DIN  1024
#define NCH  9216          // NCLS*HDIM
#define NCH4 2304          // NCH/4
#define XG_N 294912        // BSZ*NCH
#define SC_N 225792        // BSZ*NCLS*LLOC
#define SC_N4 56448        // SC_N/4
#define V_N  1179648       // BSZ*NCLS*DIN

__device__ __forceinline__ void fma4(float4& a, float s, const float4& b) {
  a.x += s * b.x; a.y += s * b.y; a.z += s * b.z; a.w += s * b.w;
}
__device__ __forceinline__ float dot4(const float4& a, const float4& b) {
  return a.x * b.x + a.y * b.y + a.z * b.z + a.w * b.w;
}

// ---------------------------------------------------------------------------
// kA: XGP[ks][b][n] = sum_{k in ks*64..+64} gap[b][k]*Wg[k][n]
// grid (36 nt256, 16 ks64), 256 thr. Wave w owns 16 k-rows; lane owns 1 f4 of
// n -> every Wg load = 1 KB contiguous, zero redundancy. 3-phase LDS reduce.
__global__ __launch_bounds__(256) void kA_xg(
    const float* __restrict__ Wg, const float* __restrict__ gap,
    float* __restrict__ XGP) {
  __shared__ __align__(16) float4 gs[512];          // [32 b][16 k4] = 8 KB
  __shared__ __align__(16) float4 red[4096];        // [2][32 b][64 lane] = 64 KB
  const int tid = threadIdx.x;
  const int nt = blockIdx.x, ks = blockIdx.y;
  const int n0 = nt * 256, k0 = ks * 64;
  const float4* gap4 = (const float4*)gap;
  for (int i = tid; i < 512; i += 256)
    gs[i] = gap4[(size_t)(i >> 4) * 256 + ks * 16 + (i & 15)];
  __syncthreads();
  const int w = tid >> 6, lane = tid & 63;
  float4 acc[32] = {};
  const float* wp = Wg + (size_t)(k0 + w * 16) * NCH + n0 + lane * 4;
  for (int kq = 0; kq < 4; ++kq) {
    float4 wr[4];
    #pragma unroll
    for (int kk = 0; kk < 4; ++kk)
      wr[kk] = *(const float4*)(wp + (size_t)(kq * 4 + kk) * NCH);
    const int k4g = w * 4 + kq;
    #pragma unroll
    for (int b = 0; b < 32; ++b) {
      float4 g = gs[b * 16 + k4g];                  // wave-wide broadcast
      fma4(acc[b], g.x, wr[0]); fma4(acc[b], g.y, wr[1]);
      fma4(acc[b], g.z, wr[2]); fma4(acc[b], g.w, wr[3]);
    }
  }
  __syncthreads();
  if (w >= 2) {
    #pragma unroll
    for (int b = 0; b < 32; ++b) red[(w - 2) * 2048 + b * 64 + lane] = acc[b];
  }
  __syncthreads();
  if (w < 2) {
    #pragma unroll
    for (int b = 0; b < 32; ++b) {
      float4 t = red[w * 2048 + b * 64 + lane];
      acc[b].x += t.x; acc[b].y += t.y; acc[b].z += t.z; acc[b].w += t.w;
    }
    #pragma unroll
    for (int b = 0; b < 32; ++b) red[w * 2048 + b * 64 + lane] = acc[b];
  }
  __syncthreads();
  #pragma unroll
  for (int i = 0; i < 8; ++i) {
    int b = w * 8 + i;
    float4 a = red[b * 64 + lane];
    float4 c = red[2048 + b * 64 + lane];
    a.x += c.x; a.y += c.y; a.z += c.z; a.w += c.w;
    *(float4*)&XGP[(size_t)ks * XG_N + (size_t)b * NCH + n0 + lane * 4] = a;
  }
}

// ---------------------------------------------------------------------------
// kB: XG = bg + sum_{p<16} XGP[p].  grid 288 x 256 (1 f4/thread).
__global__ __launch_bounds__(256) void kB_red(
    const float* __restrict__ XGP, const float* __restrict__ bg,
    float* __restrict__ XG) {
  const int b = blockIdx.x / 9;
  const int j = (blockIdx.x % 9) * 256 + threadIdx.x;   // 0..2303
  const size_t off = (size_t)b * NCH4 + j;
  const float4* p4 = (const float4*)XGP;
  float4 s = ((const float4*)bg)[j];
  #pragma unroll
  for (int p = 0; p < 16; ++p) {
    float4 t = p4[(size_t)p * (XG_N / 4) + off];
    s.x += t.x; s.y += t.y; s.z += t.z; s.w += t.w;
  }
  ((float4*)XG)[off] = s;
}

// ---------------------------------------------------------------------------
// kC: V[b][c][k] = sum_h XG[b][c,h] * Wl[k][c*256+h]
// grid (36 c, 16 kt64), 256 thr, 32 KB LDS ONLY (xg tile) -> 2+ blocks/CU.
// Wl streamed global->reg, read EXACTLY once, 4x256B segments per load.
// Lane: h16=lane&15 (h-slice), r4=lane>>4. Wave: kh=w&1 (32 k), bh=w>>1 (16 b).
// Thread tile acc[8 kk][16 b]; per h-chunk: 8 loads + 16 LDS b128 -> 512 FMA
// (32 FMA / LDS read -> VALU-bound). h-fold: 4-step cndmask butterfly over
// the 16 h16-lanes (b-dim folds; final lane holds b==h16 for all 8 kk).
__global__ __launch_bounds__(256, 2) void kC_V(
    const float* __restrict__ Wl, const float* __restrict__ XG,
    float* __restrict__ V) {
  __shared__ __align__(16) float4 xs[2048];         // [32 b][64 h4] = 32 KB
  const int tid = threadIdx.x;
  const int c = blockIdx.x, kt = blockIdx.y;
  const float4* xg4 = (const float4*)XG;
  for (int i = tid; i < 2048; i += 256) {
    int b = i >> 6, h4 = i & 63;
    xs[i] = xg4[(size_t)b * NCH4 + c * 64 + h4];    // 1 KB rows, coalesced
  }
  __syncthreads();
  const int w = tid >> 6, lane = tid & 63;
  const int h16 = lane & 15, r4 = lane >> 4;
  const int kh = w & 1, bh = w >> 1;
  const int kbase = kt * 64 + kh * 32 + r4;         // + kk*4
  float acc[8][16] = {};
  const float* wp = Wl + (size_t)kbase * NCH + c * 256 + h16 * 4;
  for (int it = 0; it < 4; ++it) {                  // h-chunks of 64
    float4 wv[8];
    #pragma unroll
    for (int kk = 0; kk < 8; ++kk)
      wv[kk] = *(const float4*)(wp + (size_t)(kk * 4) * NCH + it * 64);
    #pragma unroll
    for (int b = 0; b < 16; ++b) {
      float4 x = xs[(bh * 16 + b) * 64 + it * 16 + h16];  // 2-way max: free
      #pragma unroll
      for (int kk = 0; kk < 8; ++kk) acc[kk][b] += dot4(wv[kk], x);
    }
  }
  // butterfly fold over h16 lanes: b-dim 16 -> 1 (lane keeps b == h16)
  float f1[8][8];
  {
    const bool hb = h16 & 1;
    #pragma unroll
    for (int kk = 0; kk < 8; ++kk)
      #pragma unroll
      for (int j = 0; j < 8; ++j) {
        float keep = hb ? acc[kk][2 * j + 1] : acc[kk][2 * j];
        float send = hb ? acc[kk][2 * j]     : acc[kk][2 * j + 1];
        f1[kk][j] = keep + __shfl_xor(send, 1);
      }
  }
  float f2[8][4];
  {
    const bool hb = (h16 >> 1) & 1;
    #pragma unroll
    for (int kk = 0; kk < 8; ++kk)
      #pragma unroll
      for (int j = 0; j < 4; ++j) {
        float keep = hb ? f1[kk][2 * j + 1] : f1[kk][2 * j];
        float send = hb ? f1[kk][2 * j]     : f1[kk][2 * j + 1];
        f2[kk][j] = keep + __shfl_xor(send, 2);
      }
  }
  float f3[8][2];
  {
    const bool hb = (h16 >> 2) & 1;
    #pragma unroll
    for (int kk = 0; kk < 8; ++kk)
      #pragma unroll
      for (int j = 0; j < 2; ++j) {
        float keep = hb ? f2[kk][2 * j + 1] : f2[kk][2 * j];
        float send = hb ? f2[kk][2 * j]     : f2[kk][2 * j + 1];
        f3[kk][j] = keep + __shfl_xor(send, 4);
      }
  }
  float f4v[8];
  {
    const bool hb = (h16 >> 3) & 1;
    #pragma unroll
    for (int kk = 0; kk < 8; ++kk) {
      float keep = hb ? f3[kk][1] : f3[kk][0];
      float send = hb ? f3[kk][0] : f3[kk][1];
      f4v[kk] = keep + __shfl_xor(send, 8);
    }
  }
  const int b = bh * 16 + h16;
  float* vp = V + (size_t)(b * NCLS + c) * DIN + kbase;
  #pragma unroll
  for (int kk = 0; kk < 8; ++kk) vp[kk * 4] = f4v[kk];
}

// ---------------------------------------------------------------------------
// kD: SCP[ks][b][c][l] = sum_{k in ks*64..+64} loc[b][l][k]*V[b][c][k]
// grid (32 b, 16 ks64) = 512 (2 blocks/CU at 58 KB), 256 thr.
// loc rows rotation-swizzled; thread tile: 4 l x 9 c.
__global__ __launch_bounds__(256) void kD_scores(
    const float* __restrict__ local_f, const float* __restrict__ V,
    float* __restrict__ SCP) {
  __shared__ __align__(16) float4 loc_s[3136];      // [196][16] rot = 49 KB
  __shared__ __align__(16) float4 v_s[576];         // [36][16] = 9 KB
  const int tid = threadIdx.x;
  const int b = blockIdx.x, ks = blockIdx.y;
  const float4* lf4 = (const float4*)local_f;
  for (int i = tid; i < 3136; i += 256) {
    int r = i >> 4, g = i & 15;
    loc_s[r * 16 + ((g + r) & 15)] = lf4[(size_t)(b * LLOC + r) * 256 + ks * 16 + g];
  }
  const float4* v4 = (const float4*)V;
  for (int i = tid; i < 576; i += 256) {
    int cc = i >> 4, g = i & 15;
    v_s[i] = v4[(size_t)(b * NCLS + cc) * 256 + ks * 16 + g];
  }
  __syncthreads();
  const int lg = tid & 63, cg = tid >> 6;
  float acc[4][9] = {};
  for (int k4 = 0; k4 < 16; ++k4) {
    float4 vv[9];
    #pragma unroll
    for (int ci = 0; ci < 9; ++ci) vv[ci] = v_s[(cg * 9 + ci) * 16 + k4];
    #pragma unroll
    for (int i = 0; i < 4; ++i) {
      int l = lg + 64 * i;
      if (l < LLOC) {
        float4 a = loc_s[l * 16 + ((k4 + l) & 15)];
        #pragma unroll
        for (int ci = 0; ci < 9; ++ci) acc[i][ci] += dot4(a, vv[ci]);
      }
    }
  }
  #pragma unroll
  for (int i = 0; i < 4; ++i) {
    int l = lg + 64 * i;
    if (l < LLOC) {
      #pragma unroll
      for (int ci = 0; ci < 9; ++ci)
        SCP[(size_t)ks * SC_N + (size_t)(b * NCLS + cg * 9 + ci) * LLOC + l] = acc[i][ci];
    }
  }
}

// ---------------------------------------------------------------------------
// kE: sum 16 partials (float4) + softmax over l. grid (32,36) x 64 (49 active).
__global__ __launch_bounds__(64) void kE_softmax(
    const float* __restrict__ SCP, float* __restrict__ ATT) {
  const int b = blockIdx.x, c = blockIdx.y, t = threadIdx.x;
  const size_t base4 = (size_t)(b * NCLS + c) * 49;
  const float4* s4 = (const float4*)SCP;
  float4 s = {0.f, 0.f, 0.f, 0.f};
  float m = -1e30f;
  if (t < 49) {
    s = s4[base4 + t];
    #pragma unroll
    for (int p = 1; p < 16; ++p) {
      float4 x = s4[(size_t)p * SC_N4 + base4 + t];
      s.x += x.x; s.y += x.y; s.z += x.z; s.w += x.w;
    }
    m = fmaxf(fmaxf(s.x, s.y), fmaxf(s.z, s.w));
  }
  #pragma unroll
  for (int off = 32; off >= 1; off >>= 1) m = fmaxf(m, __shfl_xor(m, off));
  float4 e = {0.f, 0.f, 0.f, 0.f};
  float sum = 0.f;
  if (t < 49) {
    e.x = __expf(s.x - m); e.y = __expf(s.y - m);
    e.z = __expf(s.z - m); e.w = __expf(s.w - m);
    sum = e.x + e.y + e.z + e.w;
  }
  #pragma unroll
  for (int off = 32; off >= 1; off >>= 1) sum += __shfl_xor(sum, off);
  float inv = 1.0f / sum;
  if (t < 49) {
    e.x *= inv; e.y *= inv; e.z *= inv; e.w *= inv;
    ((float4*)ATT)[base4 + t] = e;
  }
}

// ---------------------------------------------------------------------------
// kF: U[b][c][k] = sum_l att[b][c][l]*loc[b][l][k]
// grid (32 b, 8 ks128) = 256, 256 thr. loc streamed from GLOBAL (coalesced,
// L3-resident after kD); att (27.6 KB) + lh-reduce (72 KB) in LDS.
__global__ __launch_bounds__(256) void kF_U(
    const float* __restrict__ local_f, const float* __restrict__ ATT,
    float* __restrict__ U) {
  __shared__ __align__(16) float4 att_s[1764];      // [36][49] = 27.6 KB
  __shared__ __align__(16) float4 red[4608];        // [4][36][32] = 72 KB
  const int tid = threadIdx.x;
  const int b = blockIdx.x, ks = blockIdx.y;
  const int k0 = ks * 128;
  const float4* at4 = (const float4*)ATT;
  for (int i = tid; i < 1764; i += 256) {
    int cc = i / 49, l4 = i - cc * 49;
    att_s[i] = at4[(size_t)(b * NCLS + cc) * 49 + l4];
  }
  __syncthreads();
  const int kg = tid & 15, cg = (tid >> 4) & 3, lh = tid >> 6;
  float4 acc[9][2] = {};
  const float* lbase = local_f + (size_t)b * LLOC * DIN + k0 + kg * 8;
  for (int l4 = lh; l4 < 49; l4 += 4) {
    float4 lv[4][2];
    #pragma unroll
    for (int ll = 0; ll < 4; ++ll) {
      const float* p = lbase + (size_t)(l4 * 4 + ll) * DIN;
      lv[ll][0] = *(const float4*)p;
      lv[ll][1] = *(const float4*)(p + 4);
    }
    #pragma unroll
    for (int ci = 0; ci < 9; ++ci) {
      float4 av = att_s[(cg * 9 + ci) * 49 + l4];
      fma4(acc[ci][0], av.x, lv[0][0]); fma4(acc[ci][1], av.x, lv[0][1]);
      fma4(acc[ci][0], av.y, lv[1][0]); fma4(acc[ci][1], av.y, lv[1][1]);
      fma4(acc[ci][0], av.z, lv[2][0]); fma4(acc[ci][1], av.z, lv[2][1]);
      fma4(acc[ci][0], av.w, lv[3][0]); fma4(acc[ci][1], av.w, lv[3][1]);
    }
  }
  #pragma unroll
  for (int ci = 0; ci < 9; ++ci) {
    int c = cg * 9 + ci;
    red[lh * 1152 + c * 32 + kg * 2 + 0] = acc[ci][0];
    red[lh * 1152 + c * 32 + kg * 2 + 1] = acc[ci][1];
  }
  __syncthreads();
  float4* u4 = (float4*)U;
  for (int i = tid; i < 1152; i += 256) {
    float4 s = red[i];
    #pragma unroll
    for (int p = 1; p < 4; ++p) {
      float4 t = red[p * 1152 + i];
      s.x += t.x; s.y += t.y; s.z += t.z; s.w += t.w;
    }
    u4[(size_t)(b * NCLS + (i >> 5)) * 256 + ks * 32 + (i & 31)] = s;
  }
}

// ---------------------------------------------------------------------------
// kG: WSP[ks][b][c*256+h] = sum_{k in ks*64..+64} U[b][c][k]*Wl[k][c*256+h]
// Exact mirror of kA. Wl read ONCE, 1 KB/instr coalesced, zero redundancy.
__global__ __launch_bounds__(256) void kG_ws(
    const float* __restrict__ Wl, const float* __restrict__ U,
    float* __restrict__ WSP) {
  __shared__ __align__(16) float4 us[512];          // [32 b][16 k4] = 8 KB
  __shared__ __align__(16) float4 red[4096];        // [2][32 b][64 lane] = 64 KB
  const int tid = threadIdx.x;
  const int c = blockIdx.x, ks = blockIdx.y;
  const int k0 = ks * 64;
  const float4* u4 = (const float4*)U;
  for (int i = tid; i < 512; i += 256)
    us[i] = u4[(size_t)((i >> 4) * NCLS + c) * 256 + ks * 16 + (i & 15)];
  __syncthreads();
  const int w = tid >> 6, lane = tid & 63;
  float4 acc[32] = {};
  const float* wp = Wl + (size_t)(k0 + w * 16) * NCH + c * HDIM + lane * 4;
  for (int kq = 0; kq < 4; ++kq) {
    float4 wr[4];
    #pragma unroll
    for (int kk = 0; kk < 4; ++kk)
      wr[kk] = *(const float4*)(wp + (size_t)(kq * 4 + kk) * NCH);
    const int k4g = w * 4 + kq;
    #pragma unroll
    for (int b = 0; b < 32; ++b) {
      float4 g = us[b * 16 + k4g];                  // wave-wide broadcast
      fma4(acc[b], g.x, wr[0]); fma4(acc[b], g.y, wr[1]);
      fma4(acc[b], g.z, wr[2]); fma4(acc[b], g.w, wr[3]);
    }
  }
  __syncthreads();
  if (w >= 2) {
    #pragma unroll
    for (int b = 0; b < 32; ++b) red[(w - 2) * 2048 + b * 64 + lane] = acc[b];
  }
  __syncthreads();
  if (w < 2) {
    #pragma unroll
    for (int b = 0; b < 32; ++b) {
      float4 t = red[w * 2048 + b * 64 + lane];
      acc[b].x += t.x; acc[b].y += t.y; acc[b].z += t.z; acc[b].w += t.w;
    }
    #pragma unroll
    for (int b = 0; b < 32; ++b) red[w * 2048 + b * 64 + lane] = acc[b];
  }
  __syncthreads();
  #pragma unroll
  for (int i = 0; i < 8; ++i) {
    int b = w * 8 + i;
    float4 a = red[b * 64 + lane];
    float4 cc = red[2048 + b * 64 + lane];
    a.x += cc.x; a.y += cc.y; a.z += cc.z; a.w += cc.w;
    *(float4*)&WSP[(size_t)ks * XG_N + (size_t)b * NCH + c * HDIM + lane * 4] = a;
  }
}

// ---------------------------------------------------------------------------
// kH: ws = bl + sum16 WSP; hid = relu(ws@Wh+bh); heads. grid (32,12) x 256.
__global__ __launch_bounds__(256) void kH_heads(
    const float* __restrict__ Wh, const float* __restrict__ bh,
    const float* __restrict__ Wr, const float* __restrict__ br,
    const float* __restrict__ Wc, const float* __restrict__ bc,
    const float* __restrict__ bl,
    const float* __restrict__ WSP, float* __restrict__ out) {
  __shared__ float ws_s[3][HDIM];
  __shared__ float hid_s[3][HDIM];
  const int b = blockIdx.x, c0 = blockIdx.y * 3;
  const int j = threadIdx.x;
  #pragma unroll
  for (int ci = 0; ci < 3; ++ci) {
    size_t base = (size_t)b * NCH + (c0 + ci) * HDIM + j;
    float s = bl[(c0 + ci) * HDIM + j];
    #pragma unroll
    for (int p = 0; p < 16; ++p) s += WSP[(size_t)p * XG_N + base];
    ws_s[ci][j] = s;
  }
  __syncthreads();
  float acc[3] = {0, 0, 0};
  for (int h = 0; h < HDIM; ++h) {
    float whj = Wh[(size_t)h * HDIM + j];
    acc[0] += ws_s[0][h] * whj;
    acc[1] += ws_s[1][h] * whj;
    acc[2] += ws_s[2][h] * whj;
  }
  float bj = bh[j];
  #pragma unroll
  for (int ci = 0; ci < 3; ++ci) hid_s[ci][j] = fmaxf(acc[ci] + bj, 0.0f);
  __syncthreads();
  const int r = j >> 6, j0 = j & 63;
  for (int ci = 0; ci < 3; ++ci) {
    const int c = c0 + ci;
    float s = 0.f;
    #pragma unroll
    for (int m = 0; m < 4; ++m)
      s += hid_s[ci][j0 + 64 * m] * Wr[(j0 + 64 * m) * 4 + r];
    #pragma unroll
    for (int off = 32; off >= 1; off >>= 1) s += __shfl_xor(s, off);
    if (j0 == 0) out[(size_t)b * (NCLS * 4) + c * 4 + r] = s + br[r];
    if (r == 0) {
      float p = 0.f;
      #pragma unroll
      for (int m = 0; m < 4; ++m)
        p += hid_s[ci][j0 + 64 * m] * Wc[j0 + 64 * m];
      #pragma unroll
      for (int off = 32; off >= 1; off >>= 1) p += __shfl_xor(p, off);
      if (j0 == 0) out[BSZ * NCLS * 4 + b * NCLS + c] = p + bc[0];
    }
  }
}

// ---------------------------------------------------------------------------
extern "C" void kernel_launch(void* const* d_in, const int* in_sizes, int n_in,
                              void* d_out, int out_size, void* d_ws, size_t ws_size,
                              hipStream_t stream) {
  const float* local = (const float*)d_in[0];
  const float* gap   = (const float*)d_in[1];
  const float* Wl    = (const float*)d_in[2];
  const float* bl    = (const float*)d_in[3];
  const float* Wg    = (const float*)d_in[4];
  const float* bg    = (const float*)d_in[5];
  const float* Wh    = (const float*)d_in[6];
  const float* bh    = (const float*)d_in[7];
  const float* Wr    = (const float*)d_in[8];
  const float* br    = (const float*)d_in[9];
  const float* Wc    = (const float*)d_in[10];
  const float* bc    = (const float*)d_in[11];
  float* out         = (float*)d_out;

  // ws: XGP 16x1.2MB | XG 1.2 | V 4.7 | SCP 16x0.9 | ATT 0.9 | U 4.7 | WSP 16x1.2
  float* XGP = (float*)d_ws;
  float* XG  = XGP + (size_t)16 * XG_N;
  float* V   = XG + XG_N;
  float* SCP = V + V_N;
  float* ATT = SCP + (size_t)16 * SC_N;
  float* U   = ATT + SC_N;
  float* WSP = U + V_N;

  kA_xg     <<<dim3(36, 16), dim3(256), 0, stream>>>(Wg, gap, XGP);
  kB_red    <<<dim3(288),    dim3(256), 0, stream>>>(XGP, bg, XG);
  kC_V      <<<dim3(36, 16), dim3(256), 0, stream>>>(Wl, XG, V);
  kD_scores <<<dim3(32, 16), dim3(256), 0, stream>>>(local, V, SCP);
  kE_softmax<<<dim3(32, 36), dim3(64),  0, stream>>>(SCP, ATT);
  kF_U      <<<dim3(32, 8),  dim3(256), 0, stream>>>(local, ATT, U);
  kG_ws     <<<dim3(36, 16), dim3(256), 0, stream>>>(Wl, U, WSP);
  kH_heads  <<<dim3(32, 12), dim3(256), 0, stream>>>(Wh, bh, Wr, br, Wc, bc, bl, WSP, out);
}